// Round 10
// baseline (752.737 us; speedup 1.0000x reference)
//
#include <hip/hip_runtime.h>
#include <cmath>

// Multi-scale residual VQ, round 27 = R26 + in-fuse argmin for pn<=4.
// R25/R26 both neutral -> fuse is NOT throughput-bound; budget re-derivation
// says ~60us of real work vs 364us wall => launch/serialization overhead
// dominates (21 dependent launches x ~10us). This round cuts launches
// 21 -> 17: scales pn=1..4 compute their argmin INSIDE fuse's prologue
// (per-block redundant, <=128 codes/thread, argsmall's exact fp32 formula,
// key-min => same selection). z ping-pongs between two halves of its
// existing 2MB region (no ws growth) to avoid the intra-launch race;
// zs emission moves to pnn>=5. pn=5,6 keep argmf; pn>=8 keep argmf4.
// Fallback path unchanged.

#define BB 64
#define CC 32
#define HH 16
#define VV 4096
#define NTOT (BB*CC*HH*HH)   // 524288
#define ABASE 163840         // atomic-slice base (entries) within bestk
#define ATOT  42624          // total atomic entries (sum B*pn^2, pn>=4)

typedef __attribute__((ext_vector_type(8))) short bf16x8;
typedef __attribute__((ext_vector_type(4))) float f32x4;

__device__ __forceinline__ double cubicw(double x) {
    x = fabs(x);
    const double a = -0.75;
    if (x <= 1.0) return ((a + 2.0) * x - (a + 3.0)) * x * x + 1.0;
    if (x < 2.0)  return (((a * x - 5.0 * a) * x + 8.0 * a) * x - 4.0 * a);
    return 0.0;
}

__device__ __forceinline__ unsigned int ordf(float d) {
    unsigned int b = __float_as_uint(d);
    return (b & 0x80000000u) ? ~b : (b | 0x80000000u);
}

__device__ __forceinline__ short f2bf(float x) {   // RNE float->bf16
    unsigned u = __float_as_uint(x);
    unsigned r = (u + 0x7fffu + ((u >> 16) & 1u)) >> 16;
    return (short)r;
}
__device__ __forceinline__ float bf2f(short h) {
    return __uint_as_float(((unsigned)(unsigned short)h) << 16);
}

// init: f_rest=f, e2 rows, z for scale 0, est splits, atomic-slice reset.
__global__ void init_k(const float* __restrict__ f, const float* __restrict__ E,
                       float* __restrict__ f_rest,
                       float* __restrict__ e2, float* __restrict__ z,
                       unsigned short* __restrict__ est,
                       unsigned long long* __restrict__ bka) {
    int i = blockIdx.x * 256 + threadIdx.x;
    if (i < NTOT) f_rest[i] = f[i];
    if (bka && i < ATOT) bka[i] = ~0ull;
    if (i < VV) {
        float s = 0.f;
        int tile = i >> 4, n = i & 15;
        #pragma unroll
        for (int c = 0; c < CC; ++c) {
            float x = E[i * CC + c];
            s += x * x;
            if (est) {
                short h = f2bf(x); float rm = x - bf2f(h);
                short m = f2bf(rm); float rl = rm - bf2f(m);
                short l = f2bf(rl);
                int idx = tile * 1536 + (n * 4 + (c >> 3)) * 8 + (c & 7);
                est[idx]        = (unsigned short)h;
                est[idx + 512]  = (unsigned short)m;
                est[idx + 1024] = (unsigned short)l;
            }
        }
        e2[i] = s;
    }
    if (i < BB * CC) {
        const float* src = f + (size_t)i * (HH * HH);
        float s = 0.f;
        for (int j = 0; j < HH * HH; ++j) s += src[j];
        z[i] = s * (1.0f / 256.0f);
    }
}

// Small scales (fallback path only): wave-uniform code range, one point
// per lane. Keys stored [m][G]; fuse reduces.
__global__ __launch_bounds__(256, 4) void argsmall_k(const float* __restrict__ z,
        const float* __restrict__ E, const float* __restrict__ e2,
        unsigned long long* __restrict__ bestk, int M, int G, int gsz) {
    const int t = threadIdx.x;
    int m = blockIdx.x * 64 + (t & 63);
    int w = __builtin_amdgcn_readfirstlane(t >> 6);
    int wg = blockIdx.y * 4 + w;
    int v0 = wg * gsz;
    float zr[CC]; float z2 = 0.f;
    const float4* zp = (const float4*)(z + (size_t)m * CC);
    #pragma unroll
    for (int c4 = 0; c4 < 8; ++c4) {
        float4 v = zp[c4];
        zr[c4*4+0] = v.x; zr[c4*4+1] = v.y; zr[c4*4+2] = v.z; zr[c4*4+3] = v.w;
        z2 += v.x*v.x + v.y*v.y + v.z*v.z + v.w*v.w;
    }
    const float* e = E + (size_t)v0 * CC;
    float best = 3.4e38f; int bv = v0;
    for (int v = v0; v < v0 + gsz; v += 2, e += 2 * CC) {
        float a0 = 0.f, a1 = 0.f, b0 = 0.f, b1 = 0.f;
        #pragma unroll
        for (int c = 0; c < CC; c += 2) {
            a0 = fmaf(zr[c],   e[c],      a0);
            a1 = fmaf(zr[c+1], e[c+1],    a1);
            b0 = fmaf(zr[c],   e[CC+c],   b0);
            b1 = fmaf(zr[c+1], e[CC+c+1], b1);
        }
        float dA = fmaf(-2.f, a0 + a1, z2 + e2[v]);
        float dB = fmaf(-2.f, b0 + b1, z2 + e2[v+1]);
        if (dA < best) { best = dA; bv = v; }
        if (dB < best) { best = dB; bv = v + 1; }
    }
    bestk[(size_t)m * G + wg] = ((unsigned long long)ordf(best) << 32) |
                                (unsigned long long)(unsigned int)bv;
}

// MFMA argmin (PTS=2), streamed with prefetch; atomicMin epilogue.
// Used for pn=5,6.
__global__ __launch_bounds__(256, 4) void argmf_k(const unsigned short* __restrict__ zs,
        const unsigned short* __restrict__ est, const float* __restrict__ e2,
        unsigned long long* __restrict__ bka, int M, int G, int gsz) {
    const int t = threadIdx.x;
    const int g = blockIdx.y;
    const int v0 = g * gsz;
    const int lane = t & 63;
    const int w = t >> 6;
    const int n = lane & 15, kq = lane >> 4;

    int tb[2]; bf16x8 ah[2], am[2], al[2];
    #pragma unroll
    for (int pt = 0; pt < 2; ++pt) {
        int tb0 = blockIdx.x * 128 + w * 32 + pt * 16;
        if (tb0 > M - 16) tb0 = M - 16;   // tail: duplicate identical work/keys
        tb[pt] = tb0;
        const unsigned short* zp = zs + (size_t)(tb0 + n) * 96 + kq * 8;
        ah[pt] = *(const bf16x8*)(zp);
        am[pt] = *(const bf16x8*)(zp + 32);
        al[pt] = *(const bf16x8*)(zp + 64);
    }

    float bd[2][4]; int bc[2][4];
    #pragma unroll
    for (int pt = 0; pt < 2; ++pt)
        #pragma unroll
        for (int r = 0; r < 4; ++r) { bd[pt][r] = 3.4e38f; bc[pt][r] = 0; }

    const int nct = gsz >> 4;
    const unsigned short* ep = est + (size_t)(v0 >> 4) * 1536 +
                               (size_t)(n * 4 + kq) * 8;
    const float* e2p = e2 + v0 + n;
    bf16x8 eh = *(const bf16x8*)(ep);
    bf16x8 em = *(const bf16x8*)(ep + 512);
    bf16x8 el = *(const bf16x8*)(ep + 1024);
    float e2c = *e2p;
    for (int ct = 0; ct < nct; ++ct) {
        bf16x8 ceh = eh, cem = em, cel = el; float ce2 = e2c;
        if (ct + 1 < nct) {          // prefetch next fragment triple
            ep += 1536; e2p += 16;
            eh = *(const bf16x8*)(ep);
            em = *(const bf16x8*)(ep + 512);
            el = *(const bf16x8*)(ep + 1024);
            e2c = *e2p;
        }
        #pragma unroll
        for (int pt = 0; pt < 2; ++pt) {
            f32x4 Ca = {0.f, 0.f, 0.f, 0.f};
            f32x4 Cb = {ce2, ce2, ce2, ce2};
            Ca = __builtin_amdgcn_mfma_f32_16x16x32_bf16(ah[pt], ceh, Ca, 0, 0, 0);
            Cb = __builtin_amdgcn_mfma_f32_16x16x32_bf16(am[pt], ceh, Cb, 0, 0, 0);
            Ca = __builtin_amdgcn_mfma_f32_16x16x32_bf16(ah[pt], cem, Ca, 0, 0, 0);
            Cb = __builtin_amdgcn_mfma_f32_16x16x32_bf16(al[pt], ceh, Cb, 0, 0, 0);
            Ca = __builtin_amdgcn_mfma_f32_16x16x32_bf16(ah[pt], cel, Ca, 0, 0, 0);
            Cb = __builtin_amdgcn_mfma_f32_16x16x32_bf16(am[pt], cem, Cb, 0, 0, 0);
            #pragma unroll
            for (int r = 0; r < 4; ++r) {
                float d = Ca[r] + Cb[r];
                if (d < bd[pt][r]) { bd[pt][r] = d; bc[pt][r] = ct; }
            }
        }
    }
    #pragma unroll
    for (int pt = 0; pt < 2; ++pt) {
        #pragma unroll
        for (int r = 0; r < 4; ++r) {
            int v = v0 + bc[pt][r] * 16 + n;
            unsigned long long k = ((unsigned long long)ordf(bd[pt][r]) << 32) |
                                   (unsigned long long)(unsigned int)v;
            #pragma unroll
            for (int msk = 1; msk < 16; msk <<= 1) {
                unsigned long long o = __shfl_xor(k, msk);
                if (o < k) k = o;
            }
            if (n == 0)
                atomicMin(&bka[(size_t)(tb[pt] + kq * 4 + r)], k);
        }
    }
}

// MFMA argmin (PTS=4): higher arithmetic intensity for big M (pn>=8).
__global__ __launch_bounds__(256, 2) void argmf4_k(const unsigned short* __restrict__ zs,
        const unsigned short* __restrict__ est, const float* __restrict__ e2,
        unsigned long long* __restrict__ bka, int M, int G, int gsz) {
    const int t = threadIdx.x;
    const int g = blockIdx.y;
    const int v0 = g * gsz;
    const int lane = t & 63;
    const int w = t >> 6;
    const int n = lane & 15, kq = lane >> 4;

    int tb[4]; bf16x8 ah[4], am[4], al[4];
    #pragma unroll
    for (int pt = 0; pt < 4; ++pt) {
        int tb0 = blockIdx.x * 256 + w * 64 + pt * 16;
        if (tb0 > M - 16) tb0 = M - 16;   // tail: duplicate identical work/keys
        tb[pt] = tb0;
        const unsigned short* zp = zs + (size_t)(tb0 + n) * 96 + kq * 8;
        ah[pt] = *(const bf16x8*)(zp);
        am[pt] = *(const bf16x8*)(zp + 32);
        al[pt] = *(const bf16x8*)(zp + 64);
    }

    float bd[4][4]; int bc[4][4];
    #pragma unroll
    for (int pt = 0; pt < 4; ++pt)
        #pragma unroll
        for (int r = 0; r < 4; ++r) { bd[pt][r] = 3.4e38f; bc[pt][r] = 0; }

    const int nct = gsz >> 4;
    const unsigned short* ep = est + (size_t)(v0 >> 4) * 1536 +
                               (size_t)(n * 4 + kq) * 8;
    const float* e2p = e2 + v0 + n;
    bf16x8 eh = *(const bf16x8*)(ep);
    bf16x8 em = *(const bf16x8*)(ep + 512);
    bf16x8 el = *(const bf16x8*)(ep + 1024);
    float e2c = *e2p;
    for (int ct = 0; ct < nct; ++ct) {
        bf16x8 ceh = eh, cem = em, cel = el; float ce2 = e2c;
        if (ct + 1 < nct) {          // prefetch next fragment triple
            ep += 1536; e2p += 16;
            eh = *(const bf16x8*)(ep);
            em = *(const bf16x8*)(ep + 512);
            el = *(const bf16x8*)(ep + 1024);
            e2c = *e2p;
        }
        #pragma unroll
        for (int pt = 0; pt < 4; ++pt) {
            f32x4 Ca = {0.f, 0.f, 0.f, 0.f};
            f32x4 Cb = {ce2, ce2, ce2, ce2};
            Ca = __builtin_amdgcn_mfma_f32_16x16x32_bf16(ah[pt], ceh, Ca, 0, 0, 0);
            Cb = __builtin_amdgcn_mfma_f32_16x16x32_bf16(am[pt], ceh, Cb, 0, 0, 0);
            Ca = __builtin_amdgcn_mfma_f32_16x16x32_bf16(ah[pt], cem, Ca, 0, 0, 0);
            Cb = __builtin_amdgcn_mfma_f32_16x16x32_bf16(al[pt], ceh, Cb, 0, 0, 0);
            Ca = __builtin_amdgcn_mfma_f32_16x16x32_bf16(ah[pt], cel, Ca, 0, 0, 0);
            Cb = __builtin_amdgcn_mfma_f32_16x16x32_bf16(am[pt], cem, Cb, 0, 0, 0);
            #pragma unroll
            for (int r = 0; r < 4; ++r) {
                float d = Ca[r] + Cb[r];
                if (d < bd[pt][r]) { bd[pt][r] = d; bc[pt][r] = ct; }
            }
        }
    }
    #pragma unroll
    for (int pt = 0; pt < 4; ++pt) {
        #pragma unroll
        for (int r = 0; r < 4; ++r) {
            int v = v0 + bc[pt][r] * 16 + n;
            unsigned long long k = ((unsigned long long)ordf(bd[pt][r]) << 32) |
                                   (unsigned long long)(unsigned int)v;
            #pragma unroll
            for (int msk = 1; msk < 16; msk <<= 1) {
                unsigned long long o = __shfl_xor(k, msk);
                if (o < k) k = o;
            }
            if (n == 0)
                atomicMin(&bka[(size_t)(tb[pt] + kq * 4 + r)], k);
        }
    }
}

// Fallback big-scale argmin (R12/R15-proven): LDS E tile, float4 reads.
__global__ __launch_bounds__(256, 4) void argbig_k(const float* __restrict__ z,
        const float* __restrict__ E, const float* __restrict__ e2,
        unsigned long long* __restrict__ bestk, int M, int G, int gsz) {
    __shared__ float s_e[128 * CC];
    __shared__ float s_e2[128];
    const int T = gridDim.x * 256;
    const int g = blockIdx.y;
    const int v0 = g * gsz;
    {
        const float4* src = (const float4*)(E + (size_t)v0 * CC);
        float4* dst = (float4*)s_e;
        for (int i = threadIdx.x; i < gsz * 8; i += 256) dst[i] = src[i];
        if (threadIdx.x < gsz) s_e2[threadIdx.x] = e2[v0 + threadIdx.x];
    }
    int   mm[2];
    bool  act[2];
    float zr[2][CC];
    float z2[2];
    #pragma unroll
    for (int pt = 0; pt < 2; ++pt) {
        int m0 = blockIdx.x * 256 + threadIdx.x + pt * T;
        act[pt] = (m0 < M);
        int m = act[pt] ? m0 : M - 1;
        mm[pt] = m;
        const float4* zp = (const float4*)(z + (size_t)m * CC);
        float zz = 0.f;
        #pragma unroll
        for (int c4 = 0; c4 < 8; ++c4) {
            float4 v = zp[c4];
            zr[pt][c4*4+0] = v.x; zr[pt][c4*4+1] = v.y;
            zr[pt][c4*4+2] = v.z; zr[pt][c4*4+3] = v.w;
            zz += v.x*v.x + v.y*v.y + v.z*v.z + v.w*v.w;
        }
        z2[pt] = zz;
    }
    __syncthreads();
    float best[2]; int bv[2];
    #pragma unroll
    for (int pt = 0; pt < 2; ++pt) { best[pt] = 3.4e38f; bv[pt] = v0; }
    const float4* ev = (const float4*)s_e;
    for (int vi = 0; vi < gsz; ++vi, ev += 8) {
        float4 e0 = ev[0], e1 = ev[1], e2v = ev[2], e3 = ev[3];
        float4 e4 = ev[4], e5 = ev[5], e6v = ev[6], e7 = ev[7];
        float ef[CC] = {e0.x,e0.y,e0.z,e0.w, e1.x,e1.y,e1.z,e1.w,
                        e2v.x,e2v.y,e2v.z,e2v.w, e3.x,e3.y,e3.z,e3.w,
                        e4.x,e4.y,e4.z,e4.w, e5.x,e5.y,e5.z,e5.w,
                        e6v.x,e6v.y,e6v.z,e6v.w, e7.x,e7.y,e7.z,e7.w};
        float a0 = 0.f, a1 = 0.f, b0 = 0.f, b1 = 0.f;
        #pragma unroll
        for (int c = 0; c < CC; c += 2) {
            a0 = fmaf(zr[0][c],   ef[c],   a0);
            a1 = fmaf(zr[0][c+1], ef[c+1], a1);
            b0 = fmaf(zr[1][c],   ef[c],   b0);
            b1 = fmaf(zr[1][c+1], ef[c+1], b1);
        }
        float e2c = s_e2[vi];
        float dA = fmaf(-2.f, a0 + a1, z2[0] + e2c);
        float dB = fmaf(-2.f, b0 + b1, z2[1] + e2c);
        int v = v0 + vi;
        if (dA < best[0]) { best[0] = dA; bv[0] = v; }
        if (dB < best[1]) { best[1] = dB; bv[1] = v; }
    }
    #pragma unroll
    for (int pt = 0; pt < 2; ++pt)
        if (act[pt])
            bestk[(size_t)mm[pt] * G + g] =
                ((unsigned long long)ordf(best[pt]) << 32) |
                (unsigned long long)(unsigned int)bv[pt];
}

// Fused (512 threads, 8 waves). G==0: atomic slice holds final key.
// G<0: in-fuse argmin over all VV codes (small scales, mf path).
// G>0: store path (fallback). Last scale writes out = f - f_rest_new.
__global__ __launch_bounds__(512) void fuse_k(const unsigned long long* __restrict__ bestk,
                      const float* __restrict__ E,
                      const float* __restrict__ pw, const float* __restrict__ pb,
                      const float* __restrict__ fsrc, float* __restrict__ fout,
                      float* __restrict__ f_rest,
                      const float* __restrict__ z_in, const float* __restrict__ e2g,
                      float* __restrict__ z_next, unsigned short* __restrict__ zsn,
                      int pn, int G, int TPP, int kphi, int pnn) {
    __shared__ float s_buf[CC * 18 * 20];     // 46KB: halo x-hat + pool scratch
    __shared__ float s_scratch[256 * 36];     // 36KB: s_vert, then s_part
    __shared__ float s_pw[CC * 3 * 4 * 8];    // 12KB: [ci][kh][cp][ce*4+kw]
    __shared__ int   s_idx[256];
    __shared__ float s_w[HH][4];
    __shared__ int   s_j[HH][4];
    __shared__ unsigned long long s_red[256];
    const int t   = threadIdx.x;
    const int cog = blockIdx.x;
    const int b   = blockIdx.y;
    const int P   = pn * pn;
    const int half = t >> 8;
    const int tl   = t & 255;

    if (G == 0) {   // atomic path: slice already holds the final key
        if (t < P)
            s_idx[t] = (int)(unsigned int)(bestk[(size_t)b * P + t] & 0xffffffffull);
    } else if (G < 0) {   // in-fuse argmin: full codebook, argsmall's formula
        int p = t / TPP, sub = t - p * TPP;
        unsigned long long bk = ~0ull;
        if (p < P) {
            float zr[CC]; float z2 = 0.f;
            const float4* zp4 = (const float4*)(z_in + (size_t)(b * P + p) * CC);
            #pragma unroll
            for (int c4 = 0; c4 < 8; ++c4) {
                float4 v4 = zp4[c4];
                zr[c4*4+0] = v4.x; zr[c4*4+1] = v4.y;
                zr[c4*4+2] = v4.z; zr[c4*4+3] = v4.w;
                z2 += v4.x*v4.x + v4.y*v4.y + v4.z*v4.z + v4.w*v4.w;
            }
            const float* e = E + (size_t)sub * CC;
            for (int v = sub; v < VV; v += TPP, e += (size_t)TPP * CC) {
                float a0 = 0.f, a1 = 0.f;
                #pragma unroll
                for (int c = 0; c < CC; c += 2) {
                    a0 = fmaf(zr[c],   e[c],   a0);
                    a1 = fmaf(zr[c+1], e[c+1], a1);
                }
                float dA = fmaf(-2.f, a0 + a1, z2 + e2g[v]);
                unsigned long long k = ((unsigned long long)ordf(dA) << 32) |
                                       (unsigned long long)(unsigned int)v;
                if (k < bk) bk = k;
            }
        }
        int bfly = TPP > 64 ? 64 : TPP;
        for (int msk = 1; msk < bfly; msk <<= 1) {
            unsigned long long o = __shfl_xor(bk, msk);
            if (o < bk) bk = o;
        }
        if (p < P) {
            if (TPP <= 64) {
                if (sub == 0) s_red[p] = bk;
            } else {
                int K = TPP >> 6;
                if ((sub & 63) == 0) s_red[p * K + (sub >> 6)] = bk;
            }
        }
    } else {        // store path: wave butterfly + ONE barrier
        int p = t / TPP, sub = t - p * TPP;
        unsigned long long bk = ~0ull;
        if (p < P) {
            const unsigned long long* kp = bestk + (size_t)(b * P + p) * G;
            for (int gg = sub; gg < G; gg += TPP) {
                unsigned long long o = kp[gg];
                if (o < bk) bk = o;
            }
        }
        int bfly = TPP > 64 ? 64 : TPP;
        for (int msk = 1; msk < bfly; msk <<= 1) {
            unsigned long long o = __shfl_xor(bk, msk);
            if (o < bk) bk = o;
        }
        if (p < P) {
            if (TPP <= 64) {
                if (sub == 0) s_red[p] = bk;
            } else {
                int K = TPP >> 6;
                if ((sub & 63) == 0) s_red[p * K + (sub >> 6)] = bk;
            }
        }
    }
    if (t < HH) {
        double src = (t + 0.5) * (double)pn / 16.0 - 0.5;
        double fi = floor(src); int i0 = (int)fi; double tt = src - fi;
        #pragma unroll
        for (int k = 0; k < 4; ++k) {
            int j = i0 - 1 + k; j = j < 0 ? 0 : (j > pn - 1 ? pn - 1 : j);
            s_j[t][k] = j;
            s_w[t][k] = (float)cubicw((double)(k - 1) - tt);
        }
    }
    {
        // pack: s_pw[ci*96 + kh*32 + cp*8 + ce*4 + kw]
        const float* src = pw + ((size_t)(kphi * CC + cog * 8)) * CC * 9;
        for (int i = t; i < 8 * CC * 9; i += 512) {
            int l  = i / (CC * 9);           // co-local 0..7
            int r  = i - l * (CC * 9);       // ci*9 + kh*3 + kw
            int ci = r / 9; int kk = r - ci * 9;
            int kh = kk / 3; int kw = kk - kh * 3;
            int cp = l >> 1, ce = l & 1;
            s_pw[ci * 96 + kh * 32 + cp * 8 + ce * 4 + kw] = src[i];
        }
    }
    __syncthreads();
    if (G != 0 && t < P) {
        unsigned long long r = s_red[(TPP <= 64) ? t : t * (TPP >> 6)];
        if (TPP > 64) {
            int K = TPP >> 6;
            for (int j2 = 1; j2 < K; ++j2) {
                unsigned long long o = s_red[t * K + j2];
                if (o < r) r = o;
            }
        }
        s_idx[t] = (int)(unsigned int)(r & 0xffffffffull);
    }
    if (G != 0) __syncthreads();

    if (tl < HH * pn) {   // vertical upsample -> pos-major s_vert
        int h = tl / pn, q = tl % pn;
        int cbase = half * 16;
        float acc[16];
        #pragma unroll
        for (int c = 0; c < 16; ++c) acc[c] = 0.f;
        #pragma unroll
        for (int k = 0; k < 4; ++k) {
            float wv = s_w[h][k];
            if (wv == 0.0f) continue;
            int row = s_idx[s_j[h][k] * pn + q];
            const float4* er = (const float4*)(E + (size_t)row * CC + cbase);
            #pragma unroll
            for (int c4 = 0; c4 < 4; ++c4) {
                float4 e4 = er[c4];
                acc[c4*4+0] = fmaf(wv, e4.x, acc[c4*4+0]);
                acc[c4*4+1] = fmaf(wv, e4.y, acc[c4*4+1]);
                acc[c4*4+2] = fmaf(wv, e4.z, acc[c4*4+2]);
                acc[c4*4+3] = fmaf(wv, e4.w, acc[c4*4+3]);
            }
        }
        float* dst = &s_scratch[(h * pn + q) * 36 + cbase];
        *(float4*)(dst + 0)  = make_float4(acc[0],  acc[1],  acc[2],  acc[3]);
        *(float4*)(dst + 4)  = make_float4(acc[4],  acc[5],  acc[6],  acc[7]);
        *(float4*)(dst + 8)  = make_float4(acc[8],  acc[9],  acc[10], acc[11]);
        *(float4*)(dst + 12) = make_float4(acc[12], acc[13], acc[14], acc[15]);
    }
    __syncthreads();

    {   // horizontal upsample: b128 reads from s_vert, write halo s_buf
        int h = tl >> 4, w = tl & 15;
        int cbase = half * 16;
        float acc[16];
        #pragma unroll
        for (int c = 0; c < 16; ++c) acc[c] = 0.f;
        #pragma unroll
        for (int k = 0; k < 4; ++k) {
            float wh = s_w[w][k];
            int j = s_j[w][k];
            const float4* sp4 = (const float4*)&s_scratch[(h * pn + j) * 36 + cbase];
            float4 v0 = sp4[0], v1 = sp4[1], v2 = sp4[2], v3 = sp4[3];
            acc[0]  = fmaf(wh, v0.x, acc[0]);  acc[1]  = fmaf(wh, v0.y, acc[1]);
            acc[2]  = fmaf(wh, v0.z, acc[2]);  acc[3]  = fmaf(wh, v0.w, acc[3]);
            acc[4]  = fmaf(wh, v1.x, acc[4]);  acc[5]  = fmaf(wh, v1.y, acc[5]);
            acc[6]  = fmaf(wh, v1.z, acc[6]);  acc[7]  = fmaf(wh, v1.w, acc[7]);
            acc[8]  = fmaf(wh, v2.x, acc[8]);  acc[9]  = fmaf(wh, v2.y, acc[9]);
            acc[10] = fmaf(wh, v2.z, acc[10]); acc[11] = fmaf(wh, v2.w, acc[11]);
            acc[12] = fmaf(wh, v3.x, acc[12]); acc[13] = fmaf(wh, v3.y, acc[13]);
            acc[14] = fmaf(wh, v3.z, acc[14]); acc[15] = fmaf(wh, v3.w, acc[15]);
        }
        #pragma unroll
        for (int c = 0; c < 16; ++c)
            s_buf[((cbase + c) * 18 + h + 1) * 20 + w + 1] = acc[c];
        if (w == 0) {
            #pragma unroll
            for (int c = 0; c < 16; ++c) s_buf[((cbase + c) * 18 + h + 1) * 20] = 0.f;
        }
        if (w >= 13) {
            #pragma unroll
            for (int c = 0; c < 16; ++c) s_buf[((cbase + c) * 18 + h + 1) * 20 + w + 4] = 0.f;
        }
        if (h == 0) {
            #pragma unroll
            for (int c = 0; c < 16; ++c) {
                s_buf[((cbase + c) * 18) * 20 + w] = 0.f;
                if (w < 4) s_buf[((cbase + c) * 18) * 20 + 16 + w] = 0.f;
            }
        }
        if (h == 15) {
            #pragma unroll
            for (int c = 0; c < 16; ++c) {
                s_buf[((cbase + c) * 18 + 17) * 20 + w] = 0.f;
                if (w < 4) s_buf[((cbase + c) * 18 + 17) * 20 + 16 + w] = 0.f;
            }
        }
    }
    __syncthreads();

    // conv: broadcast-aware mapping. wave=(wid, cp-half), lane=(cp-bit, s)
    const int wave = t >> 6;
    const int lane = t & 63;
    const int cp   = ((wave & 1) << 1) | (lane >> 5);   // 0..3 (co-pair)
    const int s    = lane & 31;
    const int h    = s >> 1;
    const int w0   = (s & 1) * 8;
    const int wid  = wave >> 1;       // 0..3 (ci quarter), wave-uniform
    const int pos  = cp * 32 + s;     // 0..127
    const int stag = wave & 1;        // kh bank stagger
    float accE[8], accO[8];
    #pragma unroll
    for (int o = 0; o < 8; ++o) { accE[o] = 0.f; accO[o] = 0.f; }
    const int ci0 = wid * 8;
    for (int ci = ci0; ci < ci0 + 8; ++ci) {
        const float* wrow = &s_pw[ci * 96 + cp * 8];
        #pragma unroll
        for (int kk = 0; kk < 3; ++kk) {
            int kh = kk + stag; kh = (kh >= 3) ? kh - 3 : kh;
            const float4* xr = (const float4*)&s_buf[(ci * 18 + h + kh) * 20 + w0];
            float4 a0 = xr[0], a1 = xr[1], a2 = xr[2];
            float xf[12] = {a0.x, a0.y, a0.z, a0.w, a1.x, a1.y, a1.z, a1.w,
                            a2.x, a2.y, a2.z, a2.w};
            const float4* wp = (const float4*)(wrow + kh * 32);
            float4 wA = wp[0];   // co-even taps
            float4 wB = wp[1];   // co-odd taps
            #pragma unroll
            for (int o = 0; o < 8; ++o) {
                accE[o] += xf[o] * wA.x + xf[o+1] * wA.y + xf[o+2] * wA.z;
                accO[o] += xf[o] * wB.x + xf[o+1] * wB.y + xf[o+2] * wB.z;
            }
        }
    }
    if (wid != 0) {
        float* dst = &s_scratch[((wid - 1) * 128 + pos) * 20];
        *(float4*)(dst +  0) = make_float4(accE[0], accE[1], accE[2], accE[3]);
        *(float4*)(dst +  4) = make_float4(accE[4], accE[5], accE[6], accE[7]);
        *(float4*)(dst +  8) = make_float4(accO[0], accO[1], accO[2], accO[3]);
        *(float4*)(dst + 12) = make_float4(accO[4], accO[5], accO[6], accO[7]);
    }
    __syncthreads();

    float4 rE0, rE1, rO0, rO1;
    if (wid == 0) {
        #pragma unroll
        for (int g2 = 0; g2 < 3; ++g2) {
            const float* sp = &s_scratch[(g2 * 128 + pos) * 20];
            float4 p0 = *(const float4*)(sp + 0), p1 = *(const float4*)(sp + 4);
            float4 p2 = *(const float4*)(sp + 8), p3 = *(const float4*)(sp + 12);
            accE[0] += p0.x; accE[1] += p0.y; accE[2] += p0.z; accE[3] += p0.w;
            accE[4] += p1.x; accE[5] += p1.y; accE[6] += p1.z; accE[7] += p1.w;
            accO[0] += p2.x; accO[1] += p2.y; accO[2] += p2.z; accO[3] += p2.w;
            accO[4] += p3.x; accO[5] += p3.y; accO[6] += p3.z; accO[7] += p3.w;
        }
        float biasE = pb[kphi * CC + cog * 8 + cp * 2];
        float biasO = pb[kphi * CC + cog * 8 + cp * 2 + 1];
        #pragma unroll
        for (int o = 0; o < 8; ++o) { accE[o] += biasE; accO[o] += biasO; }
        #pragma unroll
        for (int c = 0; c < 2; ++c) {
            const float* acc = c ? accO : accE;
            int co = cog * 8 + cp * 2 + c;
            float hf[8];
            #pragma unroll
            for (int o = 0; o < 8; ++o) {
                float hv = s_buf[(co * 18 + h + 1) * 20 + w0 + o + 1];
                hf[o] = 0.5f * hv + 0.5f * acc[o];
            }
            size_t base = ((size_t)(b * CC + co) * HH + h) * HH + w0;
            float4* fr = (float4*)(f_rest + base);
            float4 r0 = fr[0], r1 = fr[1];
            r0.x -= hf[0]; r0.y -= hf[1]; r0.z -= hf[2]; r0.w -= hf[3];
            r1.x -= hf[4]; r1.y -= hf[5]; r1.z -= hf[6]; r1.w -= hf[7];
            if (pnn > 0) {
                fr[0] = r0; fr[1] = r1;
            } else {
                // last scale: out = f - f_rest_new (f_rest itself is dead)
                const float4* fs = (const float4*)(fsrc + base);
                float4 s0 = fs[0], s1 = fs[1];
                float4 o0, o1;
                o0.x = s0.x - r0.x; o0.y = s0.y - r0.y;
                o0.z = s0.z - r0.z; o0.w = s0.w - r0.w;
                o1.x = s1.x - r1.x; o1.y = s1.y - r1.y;
                o1.z = s1.z - r1.z; o1.w = s1.w - r1.w;
                float4* fo = (float4*)(fout + base);
                fo[0] = o0; fo[1] = o1;
            }
            if (c) { rO0 = r0; rO1 = r1; } else { rE0 = r0; rE1 = r1; }
        }
    }

    if (pnn > 0) {
        __syncthreads();
        float* fn = s_buf;
        if (wid == 0) {
            #pragma unroll
            for (int c = 0; c < 2; ++c) {
                int cl = cp * 2 + c;
                float* d = &fn[(cl * HH + h) * HH + w0];
                float4 r0 = c ? rO0 : rE0, r1 = c ? rO1 : rE1;
                d[0] = r0.x; d[1] = r0.y; d[2] = r0.z; d[3] = r0.w;
                d[4] = r1.x; d[5] = r1.y; d[6] = r1.z; d[7] = r1.w;
            }
        }
        __syncthreads();
        int P2 = pnn * pnn;
        for (int i = t; i < P2 * 8; i += 512) {
            int cl = i & 7, pq = i >> 3;
            int q2 = pq % pnn, p2 = pq / pnn;
            int sp = (p2 * HH) / pnn, ep = ((p2 + 1) * HH + pnn - 1) / pnn;
            int sq = (q2 * HH) / pnn, eq = ((q2 + 1) * HH + pnn - 1) / pnn;
            float wgt = 1.0f / ((float)(ep - sp) * (float)(eq - sq));
            float sum = 0.f;
            for (int h2 = sp; h2 < ep; ++h2)
                for (int w2 = sq; w2 < eq; ++w2)
                    sum += fn[(cl * HH + h2) * HH + w2];
            float v = sum * wgt;
            int c = cog * 8 + cl;
            if (zsn) {
                float tv = -2.0f * v;        // fold -2 into the splits
                size_t baz = (size_t)(b * P2 + pq) * 96 + c;
                unsigned short hh = (unsigned short)f2bf(tv);
                float rm = tv - bf2f((short)hh);
                unsigned short mm2 = (unsigned short)f2bf(rm);
                float rl = rm - bf2f((short)mm2);
                unsigned short ll = (unsigned short)f2bf(rl);
                zsn[baz] = hh; zsn[baz + 32] = mm2; zsn[baz + 64] = ll;
            } else {
                z_next[((size_t)(b * P2 + pq)) * CC + c] = v;
            }
        }
    }
}

extern "C" void kernel_launch(void* const* d_in, const int* in_sizes, int n_in,
                              void* d_out, int out_size, void* d_ws, size_t ws_size,
                              hipStream_t stream) {
    const float* f  = (const float*)d_in[0];
    const float* E  = (const float*)d_in[1];
    const float* pw = (const float*)d_in[2];
    const float* pb = (const float*)d_in[3];
    float* out = (float*)d_out;

    // ws: f_rest | e2 | bestk(4MB: store-region + atomic slices) | z(2MB:
    //     ping-pong halves) | est(786KB) | zs(3MB)  (MFMA path)
    const size_t need_base = (size_t)(NTOT + VV) * 4 + (size_t)524288 * 8 +
                             (size_t)524288 * 4;
    const size_t need_mf = need_base + (size_t)VV * 96 * 2 +
                           (size_t)16384 * 96 * 2;
    const bool use_mf = (ws_size >= need_mf);

    float* wsf    = (float*)d_ws;
    float* f_rest = wsf;
    float* e2     = wsf + (size_t)NTOT;
    unsigned long long* bestk = (unsigned long long*)(e2 + VV);
    float* z      = (float*)(bestk + 524288);
    float* zA     = z;
    float* zB     = z + 262144;       // second half of the 2MB z region
    unsigned short* est = use_mf ? (unsigned short*)(z + 524288) : (unsigned short*)0;
    unsigned short* zs  = use_mf ? (est + (size_t)VV * 96) : (unsigned short*)0;
    unsigned long long* bka = use_mf ? (bestk + ABASE) : (unsigned long long*)0;

    int phik[10];
    {
        double start = 1.0 / 3.0 / 4.0;
        double stop  = 1.0 - 1.0 / 3.0 / 4.0;
        double step  = (stop - start) / 3.0;
        double ticks[4];
        for (int i = 0; i < 4; ++i) ticks[i] = (double)i * step + start;
        ticks[3] = stop;
        for (int si = 0; si < 10; ++si) {
            double s = (double)si / 9.0;
            int bk = 0; double bd = fabs(ticks[0] - s);
            for (int tq = 1; tq < 4; ++tq) {
                double d2 = fabs(ticks[tq] - s);
                if (d2 < bd) { bd = d2; bk = tq; }
            }
            phik[si] = bk;
        }
    }

    static const int pns[10]  = {1, 2, 3, 4, 5, 6, 8, 10, 13, 16};
    static const int grpS[10] = {256, 128, 64, 32, 32, 16, 0, 0, 0, 0};
    static const int grpF[10] = {0, 0, 0, 0, 0, 0, 128, 64, 32, 32};  // fallback
    static const int grpM[10] = {0, 0, 0, 0, 32, 32, 16, 16, 16, 16}; // MFMA path
    // atomic slice offsets (entries) for scales si=4..9
    static const int aoff[10] = {0, 0, 0, 0, 1024, 2624, 4928, 9024, 15424, 26240};

    init_k<<<(NTOT + 255) / 256, 256, 0, stream>>>(f, E, f_rest, e2, zA, est, bka);

    for (int si = 0; si < 10; ++si) {
        int pn = pns[si];
        int P = pn * pn;
        int M = BB * P;
        int G, TPP;
        const unsigned long long* fuse_bk = bestk;
        const float* zin = use_mf ? ((si & 1) ? zB : zA) : zA;
        float* zout      = use_mf ? ((si & 1) ? zA : zB) : zA;
        if (use_mf && pn <= 4) {
            // in-fuse argmin: no separate launch
            G = -1;
            TPP = 1;
            while (TPP * 2 * P <= 512) TPP *= 2;   // invariant: TPP*P <= 512
        } else if (use_mf) {
            int grp = grpM[si];
            int gsz = VV / grp;
            unsigned long long* slice = bka + aoff[si];
            if (pn >= 8) {
                int bx = (M + 255) / 256;
                argmf4_k<<<dim3(bx, grp), 256, 0, stream>>>(zs, est, e2, slice, M, grp, gsz);
            } else {
                int bx = (M + 127) / 128;
                argmf_k<<<dim3(bx, grp), 256, 0, stream>>>(zs, est, e2, slice, M, grp, gsz);
            }
            fuse_bk = slice;
            G = 0; TPP = 1;                         // fuse: direct per-point load
        } else if (pn <= 6) {
            int grp = grpS[si];
            G = grp * 4;
            int gsz = VV / G;
            argsmall_k<<<dim3(P, grp), 256, 0, stream>>>(zA, E, e2, bestk, M, G, gsz);
            TPP = 1;
            while (TPP * 2 * P <= 512) TPP *= 2;
        } else {
            G = grpF[si];
            int gsz = VV / G;
            int bx = (M + 511) / 512;
            argbig_k<<<dim3(bx, G), 256, 0, stream>>>(zA, E, e2, bestk, M, G, gsz);
            TPP = 1;
            while (TPP * 2 * P <= 512) TPP *= 2;
        }
        int pnn = (si < 9) ? pns[si + 1] : 0;
        unsigned short* zsn = (pnn >= 5 && use_mf) ? zs : (unsigned short*)0;
        fuse_k<<<dim3(4, BB), 512, 0, stream>>>(fuse_bk, E, pw, pb,
                                                f, out, f_rest,
                                                zin, e2, zout, zsn,
                                                pn, G, TPP, phik[si], pnn);
    }
}

// Round 11
// 363.302 us; speedup vs baseline: 2.0719x; 2.0719x over previous
//
#include <hip/hip_runtime.h>
#include <cmath>

// Multi-scale residual VQ, round 28 = clean revert to R26 (363.7us).
// R27 post-mortem: in-fuse argmin for pn<=4 was a 10x regression (244us
// fuse dispatches, VALUBusy 7.7%, occ 23%): at 1 block/CU the redundant
// per-block argmin is a latency-serialized critical path (128 serial
// iters x ~2000cy exposed). Separate argsmall launches spread that work
// across 512 blocks at 4x occupancy. Also: harness graph-captures, so
// launch overhead is small -- the 364us baseline is kernel time + drain,
// with fuse latency-bound at 1 block/CU (why R25/R26 were neutral).
// Future lever: fuse LDS < 80KB -> 2 blocks/CU, not launch-count games.
// Canary: absmax exactly 0.0078125, dur ~364us.

#define BB 64
#define CC 32
#define HH 16
#define VV 4096
#define NTOT (BB*CC*HH*HH)   // 524288
#define ABASE 163840         // atomic-slice base (entries) within bestk
#define ATOT  42624          // total atomic entries (sum B*pn^2, pn>=4)

typedef __attribute__((ext_vector_type(8))) short bf16x8;
typedef __attribute__((ext_vector_type(4))) float f32x4;

__device__ __forceinline__ double cubicw(double x) {
    x = fabs(x);
    const double a = -0.75;
    if (x <= 1.0) return ((a + 2.0) * x - (a + 3.0)) * x * x + 1.0;
    if (x < 2.0)  return (((a * x - 5.0 * a) * x + 8.0 * a) * x - 4.0 * a);
    return 0.0;
}

__device__ __forceinline__ unsigned int ordf(float d) {
    unsigned int b = __float_as_uint(d);
    return (b & 0x80000000u) ? ~b : (b | 0x80000000u);
}

__device__ __forceinline__ short f2bf(float x) {   // RNE float->bf16
    unsigned u = __float_as_uint(x);
    unsigned r = (u + 0x7fffu + ((u >> 16) & 1u)) >> 16;
    return (short)r;
}
__device__ __forceinline__ float bf2f(short h) {
    return __uint_as_float(((unsigned)(unsigned short)h) << 16);
}

// init: f_rest=f, e2 rows, z for scale 0, est splits, atomic-slice reset.
__global__ void init_k(const float* __restrict__ f, const float* __restrict__ E,
                       float* __restrict__ f_rest,
                       float* __restrict__ e2, float* __restrict__ z,
                       unsigned short* __restrict__ est,
                       unsigned long long* __restrict__ bka) {
    int i = blockIdx.x * 256 + threadIdx.x;
    if (i < NTOT) f_rest[i] = f[i];
    if (bka && i < ATOT) bka[i] = ~0ull;
    if (i < VV) {
        float s = 0.f;
        int tile = i >> 4, n = i & 15;
        #pragma unroll
        for (int c = 0; c < CC; ++c) {
            float x = E[i * CC + c];
            s += x * x;
            if (est) {
                short h = f2bf(x); float rm = x - bf2f(h);
                short m = f2bf(rm); float rl = rm - bf2f(m);
                short l = f2bf(rl);
                int idx = tile * 1536 + (n * 4 + (c >> 3)) * 8 + (c & 7);
                est[idx]        = (unsigned short)h;
                est[idx + 512]  = (unsigned short)m;
                est[idx + 1024] = (unsigned short)l;
            }
        }
        e2[i] = s;
    }
    if (i < BB * CC) {
        const float* src = f + (size_t)i * (HH * HH);
        float s = 0.f;
        for (int j = 0; j < HH * HH; ++j) s += src[j];
        z[i] = s * (1.0f / 256.0f);
    }
}

// Small scales (pn<=3 on MFMA path; pn<=6 on fallback): wave-uniform code
// range, one point per lane. Keys stored [m][G]; fuse reduces.
__global__ __launch_bounds__(256, 4) void argsmall_k(const float* __restrict__ z,
        const float* __restrict__ E, const float* __restrict__ e2,
        unsigned long long* __restrict__ bestk, int M, int G, int gsz) {
    const int t = threadIdx.x;
    int m = blockIdx.x * 64 + (t & 63);
    int w = __builtin_amdgcn_readfirstlane(t >> 6);
    int wg = blockIdx.y * 4 + w;
    int v0 = wg * gsz;
    float zr[CC]; float z2 = 0.f;
    const float4* zp = (const float4*)(z + (size_t)m * CC);
    #pragma unroll
    for (int c4 = 0; c4 < 8; ++c4) {
        float4 v = zp[c4];
        zr[c4*4+0] = v.x; zr[c4*4+1] = v.y; zr[c4*4+2] = v.z; zr[c4*4+3] = v.w;
        z2 += v.x*v.x + v.y*v.y + v.z*v.z + v.w*v.w;
    }
    const float* e = E + (size_t)v0 * CC;
    float best = 3.4e38f; int bv = v0;
    for (int v = v0; v < v0 + gsz; v += 2, e += 2 * CC) {
        float a0 = 0.f, a1 = 0.f, b0 = 0.f, b1 = 0.f;
        #pragma unroll
        for (int c = 0; c < CC; c += 2) {
            a0 = fmaf(zr[c],   e[c],      a0);
            a1 = fmaf(zr[c+1], e[c+1],    a1);
            b0 = fmaf(zr[c],   e[CC+c],   b0);
            b1 = fmaf(zr[c+1], e[CC+c+1], b1);
        }
        float dA = fmaf(-2.f, a0 + a1, z2 + e2[v]);
        float dB = fmaf(-2.f, b0 + b1, z2 + e2[v+1]);
        if (dA < best) { best = dA; bv = v; }
        if (dB < best) { best = dB; bv = v + 1; }
    }
    bestk[(size_t)m * G + wg] = ((unsigned long long)ordf(best) << 32) |
                                (unsigned long long)(unsigned int)bv;
}

// MFMA argmin (PTS=2), streamed with prefetch; atomicMin epilogue.
// Used for pn=4,5,6 (small M).
__global__ __launch_bounds__(256, 4) void argmf_k(const unsigned short* __restrict__ zs,
        const unsigned short* __restrict__ est, const float* __restrict__ e2,
        unsigned long long* __restrict__ bka, int M, int G, int gsz) {
    const int t = threadIdx.x;
    const int g = blockIdx.y;
    const int v0 = g * gsz;
    const int lane = t & 63;
    const int w = t >> 6;
    const int n = lane & 15, kq = lane >> 4;

    int tb[2]; bf16x8 ah[2], am[2], al[2];
    #pragma unroll
    for (int pt = 0; pt < 2; ++pt) {
        int tb0 = blockIdx.x * 128 + w * 32 + pt * 16;
        if (tb0 > M - 16) tb0 = M - 16;   // tail: duplicate identical work/keys
        tb[pt] = tb0;
        const unsigned short* zp = zs + (size_t)(tb0 + n) * 96 + kq * 8;
        ah[pt] = *(const bf16x8*)(zp);
        am[pt] = *(const bf16x8*)(zp + 32);
        al[pt] = *(const bf16x8*)(zp + 64);
    }

    float bd[2][4]; int bc[2][4];
    #pragma unroll
    for (int pt = 0; pt < 2; ++pt)
        #pragma unroll
        for (int r = 0; r < 4; ++r) { bd[pt][r] = 3.4e38f; bc[pt][r] = 0; }

    const int nct = gsz >> 4;
    const unsigned short* ep = est + (size_t)(v0 >> 4) * 1536 +
                               (size_t)(n * 4 + kq) * 8;
    const float* e2p = e2 + v0 + n;
    bf16x8 eh = *(const bf16x8*)(ep);
    bf16x8 em = *(const bf16x8*)(ep + 512);
    bf16x8 el = *(const bf16x8*)(ep + 1024);
    float e2c = *e2p;
    for (int ct = 0; ct < nct; ++ct) {
        bf16x8 ceh = eh, cem = em, cel = el; float ce2 = e2c;
        if (ct + 1 < nct) {          // prefetch next fragment triple
            ep += 1536; e2p += 16;
            eh = *(const bf16x8*)(ep);
            em = *(const bf16x8*)(ep + 512);
            el = *(const bf16x8*)(ep + 1024);
            e2c = *e2p;
        }
        #pragma unroll
        for (int pt = 0; pt < 2; ++pt) {
            f32x4 Ca = {0.f, 0.f, 0.f, 0.f};
            f32x4 Cb = {ce2, ce2, ce2, ce2};
            Ca = __builtin_amdgcn_mfma_f32_16x16x32_bf16(ah[pt], ceh, Ca, 0, 0, 0);
            Cb = __builtin_amdgcn_mfma_f32_16x16x32_bf16(am[pt], ceh, Cb, 0, 0, 0);
            Ca = __builtin_amdgcn_mfma_f32_16x16x32_bf16(ah[pt], cem, Ca, 0, 0, 0);
            Cb = __builtin_amdgcn_mfma_f32_16x16x32_bf16(al[pt], ceh, Cb, 0, 0, 0);
            Ca = __builtin_amdgcn_mfma_f32_16x16x32_bf16(ah[pt], cel, Ca, 0, 0, 0);
            Cb = __builtin_amdgcn_mfma_f32_16x16x32_bf16(am[pt], cem, Cb, 0, 0, 0);
            #pragma unroll
            for (int r = 0; r < 4; ++r) {
                float d = Ca[r] + Cb[r];
                if (d < bd[pt][r]) { bd[pt][r] = d; bc[pt][r] = ct; }
            }
        }
    }
    #pragma unroll
    for (int pt = 0; pt < 2; ++pt) {
        #pragma unroll
        for (int r = 0; r < 4; ++r) {
            int v = v0 + bc[pt][r] * 16 + n;
            unsigned long long k = ((unsigned long long)ordf(bd[pt][r]) << 32) |
                                   (unsigned long long)(unsigned int)v;
            #pragma unroll
            for (int msk = 1; msk < 16; msk <<= 1) {
                unsigned long long o = __shfl_xor(k, msk);
                if (o < k) k = o;
            }
            if (n == 0)
                atomicMin(&bka[(size_t)(tb[pt] + kq * 4 + r)], k);
        }
    }
}

// MFMA argmin (PTS=4): higher arithmetic intensity on the est stream for
// big M (pn>=8); grp=16 keeps the est slice at 49KB.
__global__ __launch_bounds__(256, 2) void argmf4_k(const unsigned short* __restrict__ zs,
        const unsigned short* __restrict__ est, const float* __restrict__ e2,
        unsigned long long* __restrict__ bka, int M, int G, int gsz) {
    const int t = threadIdx.x;
    const int g = blockIdx.y;
    const int v0 = g * gsz;
    const int lane = t & 63;
    const int w = t >> 6;
    const int n = lane & 15, kq = lane >> 4;

    int tb[4]; bf16x8 ah[4], am[4], al[4];
    #pragma unroll
    for (int pt = 0; pt < 4; ++pt) {
        int tb0 = blockIdx.x * 256 + w * 64 + pt * 16;
        if (tb0 > M - 16) tb0 = M - 16;   // tail: duplicate identical work/keys
        tb[pt] = tb0;
        const unsigned short* zp = zs + (size_t)(tb0 + n) * 96 + kq * 8;
        ah[pt] = *(const bf16x8*)(zp);
        am[pt] = *(const bf16x8*)(zp + 32);
        al[pt] = *(const bf16x8*)(zp + 64);
    }

    float bd[4][4]; int bc[4][4];
    #pragma unroll
    for (int pt = 0; pt < 4; ++pt)
        #pragma unroll
        for (int r = 0; r < 4; ++r) { bd[pt][r] = 3.4e38f; bc[pt][r] = 0; }

    const int nct = gsz >> 4;
    const unsigned short* ep = est + (size_t)(v0 >> 4) * 1536 +
                               (size_t)(n * 4 + kq) * 8;
    const float* e2p = e2 + v0 + n;
    bf16x8 eh = *(const bf16x8*)(ep);
    bf16x8 em = *(const bf16x8*)(ep + 512);
    bf16x8 el = *(const bf16x8*)(ep + 1024);
    float e2c = *e2p;
    for (int ct = 0; ct < nct; ++ct) {
        bf16x8 ceh = eh, cem = em, cel = el; float ce2 = e2c;
        if (ct + 1 < nct) {          // prefetch next fragment triple
            ep += 1536; e2p += 16;
            eh = *(const bf16x8*)(ep);
            em = *(const bf16x8*)(ep + 512);
            el = *(const bf16x8*)(ep + 1024);
            e2c = *e2p;
        }
        #pragma unroll
        for (int pt = 0; pt < 4; ++pt) {
            f32x4 Ca = {0.f, 0.f, 0.f, 0.f};
            f32x4 Cb = {ce2, ce2, ce2, ce2};
            Ca = __builtin_amdgcn_mfma_f32_16x16x32_bf16(ah[pt], ceh, Ca, 0, 0, 0);
            Cb = __builtin_amdgcn_mfma_f32_16x16x32_bf16(am[pt], ceh, Cb, 0, 0, 0);
            Ca = __builtin_amdgcn_mfma_f32_16x16x32_bf16(ah[pt], cem, Ca, 0, 0, 0);
            Cb = __builtin_amdgcn_mfma_f32_16x16x32_bf16(al[pt], ceh, Cb, 0, 0, 0);
            Ca = __builtin_amdgcn_mfma_f32_16x16x32_bf16(ah[pt], cel, Ca, 0, 0, 0);
            Cb = __builtin_amdgcn_mfma_f32_16x16x32_bf16(am[pt], cem, Cb, 0, 0, 0);
            #pragma unroll
            for (int r = 0; r < 4; ++r) {
                float d = Ca[r] + Cb[r];
                if (d < bd[pt][r]) { bd[pt][r] = d; bc[pt][r] = ct; }
            }
        }
    }
    #pragma unroll
    for (int pt = 0; pt < 4; ++pt) {
        #pragma unroll
        for (int r = 0; r < 4; ++r) {
            int v = v0 + bc[pt][r] * 16 + n;
            unsigned long long k = ((unsigned long long)ordf(bd[pt][r]) << 32) |
                                   (unsigned long long)(unsigned int)v;
            #pragma unroll
            for (int msk = 1; msk < 16; msk <<= 1) {
                unsigned long long o = __shfl_xor(k, msk);
                if (o < k) k = o;
            }
            if (n == 0)
                atomicMin(&bka[(size_t)(tb[pt] + kq * 4 + r)], k);
        }
    }
}

// Fallback big-scale argmin (R12/R15-proven): LDS E tile, float4 reads.
__global__ __launch_bounds__(256, 4) void argbig_k(const float* __restrict__ z,
        const float* __restrict__ E, const float* __restrict__ e2,
        unsigned long long* __restrict__ bestk, int M, int G, int gsz) {
    __shared__ float s_e[128 * CC];
    __shared__ float s_e2[128];
    const int T = gridDim.x * 256;
    const int g = blockIdx.y;
    const int v0 = g * gsz;
    {
        const float4* src = (const float4*)(E + (size_t)v0 * CC);
        float4* dst = (float4*)s_e;
        for (int i = threadIdx.x; i < gsz * 8; i += 256) dst[i] = src[i];
        if (threadIdx.x < gsz) s_e2[threadIdx.x] = e2[v0 + threadIdx.x];
    }
    int   mm[2];
    bool  act[2];
    float zr[2][CC];
    float z2[2];
    #pragma unroll
    for (int pt = 0; pt < 2; ++pt) {
        int m0 = blockIdx.x * 256 + threadIdx.x + pt * T;
        act[pt] = (m0 < M);
        int m = act[pt] ? m0 : M - 1;
        mm[pt] = m;
        const float4* zp = (const float4*)(z + (size_t)m * CC);
        float zz = 0.f;
        #pragma unroll
        for (int c4 = 0; c4 < 8; ++c4) {
            float4 v = zp[c4];
            zr[pt][c4*4+0] = v.x; zr[pt][c4*4+1] = v.y;
            zr[pt][c4*4+2] = v.z; zr[pt][c4*4+3] = v.w;
            zz += v.x*v.x + v.y*v.y + v.z*v.z + v.w*v.w;
        }
        z2[pt] = zz;
    }
    __syncthreads();
    float best[2]; int bv[2];
    #pragma unroll
    for (int pt = 0; pt < 2; ++pt) { best[pt] = 3.4e38f; bv[pt] = v0; }
    const float4* ev = (const float4*)s_e;
    for (int vi = 0; vi < gsz; ++vi, ev += 8) {
        float4 e0 = ev[0], e1 = ev[1], e2v = ev[2], e3 = ev[3];
        float4 e4 = ev[4], e5 = ev[5], e6v = ev[6], e7 = ev[7];
        float ef[CC] = {e0.x,e0.y,e0.z,e0.w, e1.x,e1.y,e1.z,e1.w,
                        e2v.x,e2v.y,e2v.z,e2v.w, e3.x,e3.y,e3.z,e3.w,
                        e4.x,e4.y,e4.z,e4.w, e5.x,e5.y,e5.z,e5.w,
                        e6v.x,e6v.y,e6v.z,e6v.w, e7.x,e7.y,e7.z,e7.w};
        float a0 = 0.f, a1 = 0.f, b0 = 0.f, b1 = 0.f;
        #pragma unroll
        for (int c = 0; c < CC; c += 2) {
            a0 = fmaf(zr[0][c],   ef[c],   a0);
            a1 = fmaf(zr[0][c+1], ef[c+1], a1);
            b0 = fmaf(zr[1][c],   ef[c],   b0);
            b1 = fmaf(zr[1][c+1], ef[c+1], b1);
        }
        float e2c = s_e2[vi];
        float dA = fmaf(-2.f, a0 + a1, z2[0] + e2c);
        float dB = fmaf(-2.f, b0 + b1, z2[1] + e2c);
        int v = v0 + vi;
        if (dA < best[0]) { best[0] = dA; bv[0] = v; }
        if (dB < best[1]) { best[1] = dB; bv[1] = v; }
    }
    #pragma unroll
    for (int pt = 0; pt < 2; ++pt)
        if (act[pt])
            bestk[(size_t)mm[pt] * G + g] =
                ((unsigned long long)ordf(best[pt]) << 32) |
                (unsigned long long)(unsigned int)bv[pt];
}

// Fused (512 threads, 8 waves). G==0 => bestk slice is final (one load per
// point). Conv uses broadcast-aware wave mapping.
__global__ __launch_bounds__(512) void fuse_k(const unsigned long long* __restrict__ bestk,
                      const float* __restrict__ E,
                      const float* __restrict__ pw, const float* __restrict__ pb,
                      const float* __restrict__ fsrc, float* __restrict__ fout,
                      float* __restrict__ f_rest,
                      float* __restrict__ z_next, unsigned short* __restrict__ zsn,
                      int pn, int G, int TPP, int kphi, int pnn) {
    __shared__ float s_buf[CC * 18 * 20];     // 46KB: halo x-hat + pool scratch
    __shared__ float s_scratch[256 * 36];     // 36KB: s_vert, then s_part
    __shared__ float s_pw[CC * 3 * 4 * 8];    // 12KB: [ci][kh][cp][ce*4+kw]
    __shared__ int   s_idx[256];
    __shared__ float s_w[HH][4];
    __shared__ int   s_j[HH][4];
    __shared__ unsigned long long s_red[256];
    const int t   = threadIdx.x;
    const int cog = blockIdx.x;
    const int b   = blockIdx.y;
    const int P   = pn * pn;
    const int half = t >> 8;
    const int tl   = t & 255;

    if (G == 0) {   // atomic path: slice already holds the final key
        if (t < P)
            s_idx[t] = (int)(unsigned int)(bestk[(size_t)b * P + t] & 0xffffffffull);
    } else {        // store path: wave butterfly + ONE barrier
        int p = t / TPP, sub = t - p * TPP;
        unsigned long long bk = ~0ull;
        if (p < P) {
            const unsigned long long* kp = bestk + (size_t)(b * P + p) * G;
            for (int gg = sub; gg < G; gg += TPP) {
                unsigned long long o = kp[gg];
                if (o < bk) bk = o;
            }
        }
        int bfly = TPP > 64 ? 64 : TPP;
        for (int msk = 1; msk < bfly; msk <<= 1) {
            unsigned long long o = __shfl_xor(bk, msk);
            if (o < bk) bk = o;
        }
        if (p < P) {
            if (TPP <= 64) {
                if (sub == 0) s_red[p] = bk;
            } else {
                int K = TPP >> 6;
                if ((sub & 63) == 0) s_red[p * K + (sub >> 6)] = bk;
            }
        }
    }
    if (t < HH) {
        double src = (t + 0.5) * (double)pn / 16.0 - 0.5;
        double fi = floor(src); int i0 = (int)fi; double tt = src - fi;
        #pragma unroll
        for (int k = 0; k < 4; ++k) {
            int j = i0 - 1 + k; j = j < 0 ? 0 : (j > pn - 1 ? pn - 1 : j);
            s_j[t][k] = j;
            s_w[t][k] = (float)cubicw((double)(k - 1) - tt);
        }
    }
    {
        // pack: s_pw[ci*96 + kh*32 + cp*8 + ce*4 + kw]
        const float* src = pw + ((size_t)(kphi * CC + cog * 8)) * CC * 9;
        for (int i = t; i < 8 * CC * 9; i += 512) {
            int l  = i / (CC * 9);           // co-local 0..7
            int r  = i - l * (CC * 9);       // ci*9 + kh*3 + kw
            int ci = r / 9; int kk = r - ci * 9;
            int kh = kk / 3; int kw = kk - kh * 3;
            int cp = l >> 1, ce = l & 1;
            s_pw[ci * 96 + kh * 32 + cp * 8 + ce * 4 + kw] = src[i];
        }
    }
    __syncthreads();
    if (G != 0 && t < P) {
        unsigned long long r = s_red[(TPP <= 64) ? t : t * (TPP >> 6)];
        if (TPP > 64) {
            int K = TPP >> 6;
            for (int j2 = 1; j2 < K; ++j2) {
                unsigned long long o = s_red[t * K + j2];
                if (o < r) r = o;
            }
        }
        s_idx[t] = (int)(unsigned int)(r & 0xffffffffull);
    }
    if (G != 0) __syncthreads();

    if (tl < HH * pn) {   // vertical upsample -> pos-major s_vert
        int h = tl / pn, q = tl % pn;
        int cbase = half * 16;
        float acc[16];
        #pragma unroll
        for (int c = 0; c < 16; ++c) acc[c] = 0.f;
        #pragma unroll
        for (int k = 0; k < 4; ++k) {
            float wv = s_w[h][k];
            if (wv == 0.0f) continue;
            int row = s_idx[s_j[h][k] * pn + q];
            const float4* er = (const float4*)(E + (size_t)row * CC + cbase);
            #pragma unroll
            for (int c4 = 0; c4 < 4; ++c4) {
                float4 e4 = er[c4];
                acc[c4*4+0] = fmaf(wv, e4.x, acc[c4*4+0]);
                acc[c4*4+1] = fmaf(wv, e4.y, acc[c4*4+1]);
                acc[c4*4+2] = fmaf(wv, e4.z, acc[c4*4+2]);
                acc[c4*4+3] = fmaf(wv, e4.w, acc[c4*4+3]);
            }
        }
        float* dst = &s_scratch[(h * pn + q) * 36 + cbase];
        *(float4*)(dst + 0)  = make_float4(acc[0],  acc[1],  acc[2],  acc[3]);
        *(float4*)(dst + 4)  = make_float4(acc[4],  acc[5],  acc[6],  acc[7]);
        *(float4*)(dst + 8)  = make_float4(acc[8],  acc[9],  acc[10], acc[11]);
        *(float4*)(dst + 12) = make_float4(acc[12], acc[13], acc[14], acc[15]);
    }
    __syncthreads();

    {   // horizontal upsample: b128 reads from s_vert, write halo s_buf
        int h = tl >> 4, w = tl & 15;
        int cbase = half * 16;
        float acc[16];
        #pragma unroll
        for (int c = 0; c < 16; ++c) acc[c] = 0.f;
        #pragma unroll
        for (int k = 0; k < 4; ++k) {
            float wh = s_w[w][k];
            int j = s_j[w][k];
            const float4* sp4 = (const float4*)&s_scratch[(h * pn + j) * 36 + cbase];
            float4 v0 = sp4[0], v1 = sp4[1], v2 = sp4[2], v3 = sp4[3];
            acc[0]  = fmaf(wh, v0.x, acc[0]);  acc[1]  = fmaf(wh, v0.y, acc[1]);
            acc[2]  = fmaf(wh, v0.z, acc[2]);  acc[3]  = fmaf(wh, v0.w, acc[3]);
            acc[4]  = fmaf(wh, v1.x, acc[4]);  acc[5]  = fmaf(wh, v1.y, acc[5]);
            acc[6]  = fmaf(wh, v1.z, acc[6]);  acc[7]  = fmaf(wh, v1.w, acc[7]);
            acc[8]  = fmaf(wh, v2.x, acc[8]);  acc[9]  = fmaf(wh, v2.y, acc[9]);
            acc[10] = fmaf(wh, v2.z, acc[10]); acc[11] = fmaf(wh, v2.w, acc[11]);
            acc[12] = fmaf(wh, v3.x, acc[12]); acc[13] = fmaf(wh, v3.y, acc[13]);
            acc[14] = fmaf(wh, v3.z, acc[14]); acc[15] = fmaf(wh, v3.w, acc[15]);
        }
        #pragma unroll
        for (int c = 0; c < 16; ++c)
            s_buf[((cbase + c) * 18 + h + 1) * 20 + w + 1] = acc[c];
        if (w == 0) {
            #pragma unroll
            for (int c = 0; c < 16; ++c) s_buf[((cbase + c) * 18 + h + 1) * 20] = 0.f;
        }
        if (w >= 13) {
            #pragma unroll
            for (int c = 0; c < 16; ++c) s_buf[((cbase + c) * 18 + h + 1) * 20 + w + 4] = 0.f;
        }
        if (h == 0) {
            #pragma unroll
            for (int c = 0; c < 16; ++c) {
                s_buf[((cbase + c) * 18) * 20 + w] = 0.f;
                if (w < 4) s_buf[((cbase + c) * 18) * 20 + 16 + w] = 0.f;
            }
        }
        if (h == 15) {
            #pragma unroll
            for (int c = 0; c < 16; ++c) {
                s_buf[((cbase + c) * 18 + 17) * 20 + w] = 0.f;
                if (w < 4) s_buf[((cbase + c) * 18 + 17) * 20 + 16 + w] = 0.f;
            }
        }
    }
    __syncthreads();

    // conv: broadcast-aware mapping. wave=(wid, cp-half), lane=(cp-bit, s):
    // x-reads 2-way broadcast (same s, both cp), w-reads 32-way broadcast.
    const int wave = t >> 6;
    const int lane = t & 63;
    const int cp   = ((wave & 1) << 1) | (lane >> 5);   // 0..3 (co-pair)
    const int s    = lane & 31;
    const int h    = s >> 1;
    const int w0   = (s & 1) * 8;
    const int wid  = wave >> 1;       // 0..3 (ci quarter), wave-uniform
    const int pos  = cp * 32 + s;     // 0..127
    const int stag = wave & 1;        // kh bank stagger
    float accE[8], accO[8];
    #pragma unroll
    for (int o = 0; o < 8; ++o) { accE[o] = 0.f; accO[o] = 0.f; }
    const int ci0 = wid * 8;
    for (int ci = ci0; ci < ci0 + 8; ++ci) {
        const float* wrow = &s_pw[ci * 96 + cp * 8];
        #pragma unroll
        for (int kk = 0; kk < 3; ++kk) {
            int kh = kk + stag; kh = (kh >= 3) ? kh - 3 : kh;
            const float4* xr = (const float4*)&s_buf[(ci * 18 + h + kh) * 20 + w0];
            float4 a0 = xr[0], a1 = xr[1], a2 = xr[2];
            float xf[12] = {a0.x, a0.y, a0.z, a0.w, a1.x, a1.y, a1.z, a1.w,
                            a2.x, a2.y, a2.z, a2.w};
            const float4* wp = (const float4*)(wrow + kh * 32);
            float4 wA = wp[0];   // co-even taps
            float4 wB = wp[1];   // co-odd taps
            #pragma unroll
            for (int o = 0; o < 8; ++o) {
                accE[o] += xf[o] * wA.x + xf[o+1] * wA.y + xf[o+2] * wA.z;
                accO[o] += xf[o] * wB.x + xf[o+1] * wB.y + xf[o+2] * wB.z;
            }
        }
    }
    if (wid != 0) {
        float* dst = &s_scratch[((wid - 1) * 128 + pos) * 20];
        *(float4*)(dst +  0) = make_float4(accE[0], accE[1], accE[2], accE[3]);
        *(float4*)(dst +  4) = make_float4(accE[4], accE[5], accE[6], accE[7]);
        *(float4*)(dst +  8) = make_float4(accO[0], accO[1], accO[2], accO[3]);
        *(float4*)(dst + 12) = make_float4(accO[4], accO[5], accO[6], accO[7]);
    }
    __syncthreads();

    float4 rE0, rE1, rO0, rO1;
    if (wid == 0) {
        #pragma unroll
        for (int g2 = 0; g2 < 3; ++g2) {
            const float* sp = &s_scratch[(g2 * 128 + pos) * 20];
            float4 p0 = *(const float4*)(sp + 0), p1 = *(const float4*)(sp + 4);
            float4 p2 = *(const float4*)(sp + 8), p3 = *(const float4*)(sp + 12);
            accE[0] += p0.x; accE[1] += p0.y; accE[2] += p0.z; accE[3] += p0.w;
            accE[4] += p1.x; accE[5] += p1.y; accE[6] += p1.z; accE[7] += p1.w;
            accO[0] += p2.x; accO[1] += p2.y; accO[2] += p2.z; accO[3] += p2.w;
            accO[4] += p3.x; accO[5] += p3.y; accO[6] += p3.z; accO[7] += p3.w;
        }
        float biasE = pb[kphi * CC + cog * 8 + cp * 2];
        float biasO = pb[kphi * CC + cog * 8 + cp * 2 + 1];
        #pragma unroll
        for (int o = 0; o < 8; ++o) { accE[o] += biasE; accO[o] += biasO; }
        #pragma unroll
        for (int c = 0; c < 2; ++c) {
            const float* acc = c ? accO : accE;
            int co = cog * 8 + cp * 2 + c;
            float hf[8];
            #pragma unroll
            for (int o = 0; o < 8; ++o) {
                float hv = s_buf[(co * 18 + h + 1) * 20 + w0 + o + 1];
                hf[o] = 0.5f * hv + 0.5f * acc[o];
            }
            size_t base = ((size_t)(b * CC + co) * HH + h) * HH + w0;
            float4* fr = (float4*)(f_rest + base);
            float4 r0 = fr[0], r1 = fr[1];
            r0.x -= hf[0]; r0.y -= hf[1]; r0.z -= hf[2]; r0.w -= hf[3];
            r1.x -= hf[4]; r1.y -= hf[5]; r1.z -= hf[6]; r1.w -= hf[7];
            if (pnn > 0) {
                fr[0] = r0; fr[1] = r1;
            } else {
                // last scale: out = f - f_rest_new (f_rest itself is dead)
                const float4* fs = (const float4*)(fsrc + base);
                float4 s0 = fs[0], s1 = fs[1];
                float4 o0, o1;
                o0.x = s0.x - r0.x; o0.y = s0.y - r0.y;
                o0.z = s0.z - r0.z; o0.w = s0.w - r0.w;
                o1.x = s1.x - r1.x; o1.y = s1.y - r1.y;
                o1.z = s1.z - r1.z; o1.w = s1.w - r1.w;
                float4* fo = (float4*)(fout + base);
                fo[0] = o0; fo[1] = o1;
            }
            if (c) { rO0 = r0; rO1 = r1; } else { rE0 = r0; rE1 = r1; }
        }
    }

    if (pnn > 0) {
        __syncthreads();
        float* fn = s_buf;
        if (wid == 0) {
            #pragma unroll
            for (int c = 0; c < 2; ++c) {
                int cl = cp * 2 + c;
                float* d = &fn[(cl * HH + h) * HH + w0];
                float4 r0 = c ? rO0 : rE0, r1 = c ? rO1 : rE1;
                d[0] = r0.x; d[1] = r0.y; d[2] = r0.z; d[3] = r0.w;
                d[4] = r1.x; d[5] = r1.y; d[6] = r1.z; d[7] = r1.w;
            }
        }
        __syncthreads();
        int P2 = pnn * pnn;
        for (int i = t; i < P2 * 8; i += 512) {
            int cl = i & 7, pq = i >> 3;
            int q2 = pq % pnn, p2 = pq / pnn;
            int sp = (p2 * HH) / pnn, ep = ((p2 + 1) * HH + pnn - 1) / pnn;
            int sq = (q2 * HH) / pnn, eq = ((q2 + 1) * HH + pnn - 1) / pnn;
            float wgt = 1.0f / ((float)(ep - sp) * (float)(eq - sq));
            float sum = 0.f;
            for (int h2 = sp; h2 < ep; ++h2)
                for (int w2 = sq; w2 < eq; ++w2)
                    sum += fn[(cl * HH + h2) * HH + w2];
            float v = sum * wgt;
            int c = cog * 8 + cl;
            if (zsn) {
                float tv = -2.0f * v;        // fold -2 into the splits
                size_t baz = (size_t)(b * P2 + pq) * 96 + c;
                unsigned short hh = (unsigned short)f2bf(tv);
                float rm = tv - bf2f((short)hh);
                unsigned short mm2 = (unsigned short)f2bf(rm);
                float rl = rm - bf2f((short)mm2);
                unsigned short ll = (unsigned short)f2bf(rl);
                zsn[baz] = hh; zsn[baz + 32] = mm2; zsn[baz + 64] = ll;
            } else {
                z_next[((size_t)(b * P2 + pq)) * CC + c] = v;
            }
        }
    }
}

extern "C" void kernel_launch(void* const* d_in, const int* in_sizes, int n_in,
                              void* d_out, int out_size, void* d_ws, size_t ws_size,
                              hipStream_t stream) {
    const float* f  = (const float*)d_in[0];
    const float* E  = (const float*)d_in[1];
    const float* pw = (const float*)d_in[2];
    const float* pb = (const float*)d_in[3];
    float* out = (float*)d_out;

    // ws: f_rest | e2 | bestk(4MB: store-region + atomic slices) | z(2MB)
    //     | est(786KB) | zs(3MB)  (MFMA path)
    const size_t need_base = (size_t)(NTOT + VV) * 4 + (size_t)524288 * 8 +
                             (size_t)524288 * 4;
    const size_t need_mf = need_base + (size_t)VV * 96 * 2 +
                           (size_t)16384 * 96 * 2;
    const bool use_mf = (ws_size >= need_mf);

    float* wsf    = (float*)d_ws;
    float* f_rest = wsf;
    float* e2     = wsf + (size_t)NTOT;
    unsigned long long* bestk = (unsigned long long*)(e2 + VV);
    float* z      = (float*)(bestk + 524288);
    unsigned short* est = use_mf ? (unsigned short*)(z + 524288) : (unsigned short*)0;
    unsigned short* zs  = use_mf ? (est + (size_t)VV * 96) : (unsigned short*)0;
    unsigned long long* bka = use_mf ? (bestk + ABASE) : (unsigned long long*)0;

    int phik[10];
    {
        double start = 1.0 / 3.0 / 4.0;
        double stop  = 1.0 - 1.0 / 3.0 / 4.0;
        double step  = (stop - start) / 3.0;
        double ticks[4];
        for (int i = 0; i < 4; ++i) ticks[i] = (double)i * step + start;
        ticks[3] = stop;
        for (int si = 0; si < 10; ++si) {
            double s = (double)si / 9.0;
            int bk = 0; double bd = fabs(ticks[0] - s);
            for (int tq = 1; tq < 4; ++tq) {
                double d2 = fabs(ticks[tq] - s);
                if (d2 < bd) { bd = d2; bk = tq; }
            }
            phik[si] = bk;
        }
    }

    static const int pns[10]  = {1, 2, 3, 4, 5, 6, 8, 10, 13, 16};
    static const int grpS[10] = {256, 128, 64, 32, 32, 16, 0, 0, 0, 0};
    static const int grpF[10] = {0, 0, 0, 0, 0, 0, 128, 64, 32, 32};  // fallback
    static const int grpM[10] = {0, 0, 0, 32, 32, 32, 16, 16, 16, 16}; // MFMA path
    // atomic slice offsets (entries) for scales si=3..9
    static const int aoff[10] = {0, 0, 0, 0, 1024, 2624, 4928, 9024, 15424, 26240};

    init_k<<<(NTOT + 255) / 256, 256, 0, stream>>>(f, E, f_rest, e2, z, est, bka);

    for (int si = 0; si < 10; ++si) {
        int pn = pns[si];
        int P = pn * pn;
        int M = BB * P;
        int G, TPP;
        bool small_path = use_mf ? (pn <= 3) : (pn <= 6);
        const unsigned long long* fuse_bk = bestk;
        if (small_path) {
            int grp = grpS[si];
            G = grp * 4;
            int gsz = VV / G;
            argsmall_k<<<dim3(P, grp), 256, 0, stream>>>(z, E, e2, bestk, M, G, gsz);
            TPP = 1;
            while (TPP * 2 * P <= 512) TPP *= 2;   // invariant: TPP*P <= 512
        } else if (use_mf) {
            int grp = grpM[si];
            int gsz = VV / grp;
            unsigned long long* slice = bka + aoff[si];
            if (pn >= 8) {
                int bx = (M + 255) / 256;
                argmf4_k<<<dim3(bx, grp), 256, 0, stream>>>(zs, est, e2, slice, M, grp, gsz);
            } else {
                int bx = (M + 127) / 128;
                argmf_k<<<dim3(bx, grp), 256, 0, stream>>>(zs, est, e2, slice, M, grp, gsz);
            }
            fuse_bk = slice;
            G = 0; TPP = 1;                         // fuse: direct per-point load
        } else {
            G = grpF[si];
            int gsz = VV / G;
            int bx = (M + 511) / 512;
            argbig_k<<<dim3(bx, G), 256, 0, stream>>>(z, E, e2, bestk, M, G, gsz);
            TPP = 1;
            while (TPP * 2 * P <= 512) TPP *= 2;
        }
        int pnn = (si < 9) ? pns[si + 1] : 0;
        unsigned short* zsn = (pnn >= 4 && use_mf) ? zs : (unsigned short*)0;
        fuse_k<<<dim3(4, BB), 512, 0, stream>>>(fuse_bk, E, pw, pb,
                                                f, out, f_rest, z, zsn,
                                                pn, G, TPP, phik[si], pnn);
    }
}